// Round 21
// baseline (378.049 us; speedup 1.0000x reference)
//
#include <hip/hip_runtime.h>
#include <hip/hip_fp16.h>

constexpr int HI = 256, WI = 256;   // reg_feat spatial
constexpr int HO = 512, WO = 512;   // upsampled spatial
constexpr int CI = 32;              // feat channels
constexpr int CK = 49;              // 7x7 unfold channels

// ---- ws layout (float offsets) --------------------------------------------
constexpr size_t OFF_WPC = 0;                         // w2 fp16 32x32: 26*2*64 uint4 = 13312 f32
constexpr size_t OFF_B2P = 13312;                     // padded b2 [64]
constexpr size_t OFF_WPB = 13376;                     // w1 fp16: 7*4*64 uint4 = 7168 f32
constexpr size_t OFF_B1P = 20544;                     // padded b1 [64]
constexpr size_t OFF_WPA = 20608;                     // wt fp16: 4*4*2*64 uint4 = 8192 f32
constexpr size_t OFF_F0  = 28800;                     // f0p fp16 [512][512][32]
constexpr size_t OFF_XP  = OFF_F0 + (size_t)HO * WO * CI / 2;     // xp fp16 [258][258][32]
constexpr size_t OFF_FLP = OFF_XP + (size_t)258 * 258 * 32 / 2;   // flowp f32 [2][518][518]

constexpr int FP_W = 518;            // padded flow row (512 + 3 + 3)
constexpr int XP_W = 258;            // padded x row (256 + 1 + 1)

using f16x8  = __attribute__((ext_vector_type(8))) _Float16;
using f32x4  = __attribute__((ext_vector_type(4))) float;
using f32x16 = __attribute__((ext_vector_type(16))) float;

__device__ inline unsigned short h_rne(float x) {      // fp32 -> fp16 bits (RNE)
    return __half_as_ushort(__float2half(x));
}

union FragH { uint4 q; f16x8 v; };

// ---------------------------------------------------------------------------
// kPP: x -> single fp16 plane xp [258][258][32] (zero border); flow -> flowp.
// (unchanged R19/R20)
// ---------------------------------------------------------------------------
__global__ void kPP(const float* __restrict__ x, const float* __restrict__ flow,
                    unsigned short* __restrict__ xp, float* __restrict__ flowp)
{
    const int bid = blockIdx.x;
    if (bid < XP_W) {
        const int yp = bid;
        const int y  = yp - 1;
        for (int xpc = threadIdx.x; xpc < XP_W; xpc += 256) {
            const int xc = xpc - 1;
            uint4* dst = reinterpret_cast<uint4*>(xp + ((size_t)yp * XP_W + xpc) * 32);
            if ((unsigned)y < 256u && (unsigned)xc < 256u) {
                const float* src = x + y * 256 + xc;
                unsigned w[16];
                #pragma unroll
                for (int c2 = 0; c2 < 16; ++c2) {
                    const unsigned short h0 = h_rne(src[(size_t)(2 * c2) * 65536]);
                    const unsigned short h1 = h_rne(src[(size_t)(2 * c2 + 1) * 65536]);
                    w[c2] = ((unsigned)h1 << 16) | h0;
                }
                const uint4* q = reinterpret_cast<const uint4*>(w);
                #pragma unroll
                for (int r = 0; r < 4; ++r) dst[r] = q[r];
            } else {
                #pragma unroll
                for (int r = 0; r < 4; ++r) dst[r] = make_uint4(0u, 0u, 0u, 0u);
            }
        }
    } else {
        const int idx = (bid - XP_W) * 256 + threadIdx.x;
        if (idx >= 2 * FP_W * FP_W) return;
        const int p  = idx / (FP_W * FP_W);
        const int q  = idx - p * (FP_W * FP_W);
        const int hh = q / FP_W;
        const int ww = q - hh * FP_W;
        float v = 0.f;
        const int hs = hh - 3, wsx = ww - 3;
        if ((unsigned)hs < (unsigned)HO && (unsigned)wsx < (unsigned)WO)
            v = flow[p * (HO * WO) + hs * WO + wsx];
        flowp[idx] = v;
    }
}

// ---------------------------------------------------------------------------
// repack (unchanged R20): wpA/wpB fp16 16x16; wpC fp16 32x32 encoding.
// ---------------------------------------------------------------------------
__global__ void repack(const float* __restrict__ wt,
                       const float* __restrict__ w1, const float* __restrict__ b1,
                       const float* __restrict__ w2, const float* __restrict__ b2,
                       uint4* __restrict__ wpA, uint4* __restrict__ wpB,
                       float* __restrict__ b1p, uint4* __restrict__ wpC,
                       float* __restrict__ b2p)
{
    const int j = blockIdx.x * 256 + threadIdx.x;
    if (j < 64) {
        b2p[j] = (j < CK) ? b2[j] : 1e18f;
        b1p[j] = (j < CK) ? b1[j] : 0.f;
    }
    if (j < 4 * 4 * 2 * 64) {               // kA fp16
        const int lane = j & 63;
        const int mf   = (j >> 6) & 1;
        const int tap  = (j >> 7) & 3;
        const int cls  = j >> 9;
        const int ohpar = cls >> 1, par = cls & 1;
        const int a = tap >> 1, d = tap & 1;
        const int kh = (ohpar ? 0 : 1) + 2 * a;
        const int kw = (par ? 0 : 1) + 2 * d;
        const int o = mf * 16 + (lane & 15);
        unsigned short b[8];
        #pragma unroll
        for (int jj = 0; jj < 8; ++jj) {
            const int i = (lane >> 4) * 8 + jj;
            b[jj] = h_rne(wt[((i * 32 + o) * 4 + kh) * 4 + kw]);
        }
        uint4 q;
        q.x = ((unsigned)b[1] << 16) | b[0];
        q.y = ((unsigned)b[3] << 16) | b[2];
        q.z = ((unsigned)b[5] << 16) | b[4];
        q.w = ((unsigned)b[7] << 16) | b[6];
        wpA[((cls * 4 + tap) * 2 + mf) * 64 + lane] = q;
    }
    if (j < 7 * 4 * 64) {                   // stage-1 fp16: chunk t, k = i
        const int lane = j & 63;
        const int mf   = (j >> 6) & 3;
        const int t    = j >> 8;
        const int o = mf * 16 + (lane & 15);
        unsigned short b[8];
        #pragma unroll
        for (int jj = 0; jj < 8; ++jj) {
            const int i = (lane >> 4) * 8 + jj;
            b[jj] = h_rne((o < CK) ? w1[o * 224 + i * 7 + t] : 0.f);
        }
        uint4 q;
        q.x = ((unsigned)b[1] << 16) | b[0];
        q.y = ((unsigned)b[3] << 16) | b[2];
        q.z = ((unsigned)b[5] << 16) | b[4];
        q.w = ((unsigned)b[7] << 16) | b[6];
        wpB[(t * 4 + mf) * 64 + lane] = q;
    }
    if (j < 26 * 2 * 64) {                  // stage-2 fp16, 32x32 encoding
        const int lane = j & 63;
        const int m    = (j >> 6) & 1;
        const int cc   = j >> 7;
        const int o    = m * 32 + (lane & 31);
        const int kg   = cc * 2 + (lane >> 5);
        const int oct  = kg / 7;
        const int t    = kg - 7 * oct;
        unsigned short b[8];
        #pragma unroll
        for (int jj = 0; jj < 8; ++jj) {
            const int i = oct * 8 + jj;
            float v = 0.f;
            if (kg < CK && o < CK && i < CK) v = w2[o * 343 + i * 7 + t];
            b[jj] = h_rne(v);
        }
        uint4 q;
        q.x = ((unsigned)b[1] << 16) | b[0];
        q.y = ((unsigned)b[3] << 16) | b[2];
        q.z = ((unsigned)b[5] << 16) | b[4];
        q.w = ((unsigned)b[7] << 16) | b[6];
        wpC[(cc * 2 + m) * 64 + lane] = q;
    }
}

// ---------------------------------------------------------------------------
// kA: ConvTranspose2d via fp16 MFMA (R19 body). launch_bounds(256,8):
// VGPR ~60 fits the 64 cap; LDS 20480 B x 8 = exactly 160 KiB.
// ---------------------------------------------------------------------------
__global__ __launch_bounds__(256, 8)
void kA(const unsigned short* __restrict__ xp, const uint4* __restrict__ wpA,
        const float* __restrict__ bt, unsigned short* __restrict__ f0p)
{
    __shared__ unsigned ep[4][64 * 20];     // [px][16 u32 fp16-pairs + 4 pad]

    const int tid  = threadIdx.x;
    const int oh   = blockIdx.x >> 1;
    const int half = blockIdx.x & 1;
    const int wv   = tid >> 6;
    const int lane = tid & 63;
    const int col  = lane & 15;
    const int g    = lane >> 4;
    const int par  = wv >> 1;
    const int n0   = half * 128 + (wv & 1) * 64;

    const int ohpar = oh & 1;
    const int kh0   = ohpar ? 0 : 1;
    const int ihA   = (oh + 1 - kh0) >> 1;
    const int cls   = ohpar * 2 + par;
    const int ioff  = par ? 2 : 1;

    f32x4 acc[2][4];
    #pragma unroll
    for (int mf = 0; mf < 2; ++mf)
        #pragma unroll
        for (int nf = 0; nf < 4; ++nf)
            acc[mf][nf] = (f32x4){0.f, 0.f, 0.f, 0.f};

    #pragma unroll
    for (int a = 0; a < 2; ++a) {
        const int rowbase = (ihA + 1 - a) * XP_W;
        #pragma unroll
        for (int d = 0; d < 2; ++d) {
            FragH B[4];
            #pragma unroll
            for (int nf = 0; nf < 4; ++nf) {
                const size_t base =
                    ((size_t)(rowbase + n0 + nf * 16 + col + ioff - d)) * 32 + g * 8;
                B[nf].q = *reinterpret_cast<const uint4*>(xp + base);
            }
            const int tap = a * 2 + d;
            #pragma unroll
            for (int mf = 0; mf < 2; ++mf) {
                FragH ah;
                ah.q = wpA[((cls * 4 + tap) * 2 + mf) * 64 + lane];
                #pragma unroll
                for (int nf = 0; nf < 4; ++nf)
                    acc[mf][nf] = __builtin_amdgcn_mfma_f32_16x16x32_f16(ah.v, B[nf].v, acc[mf][nf], 0, 0, 0);
            }
        }
    }

    unsigned* myep = ep[wv];
    #pragma unroll
    for (int mf = 0; mf < 2; ++mf)
        #pragma unroll
        for (int nf = 0; nf < 4; ++nf) {
            unsigned short hv[4];
            #pragma unroll
            for (int r = 0; r < 4; ++r) {
                const int ch = mf * 16 + g * 4 + r;
                hv[r] = h_rne(acc[mf][nf][r] + bt[ch]);
            }
            unsigned* row = myep + (nf * 16 + col) * 20;
            const int cp = mf * 8 + g * 2;
            row[cp]     = ((unsigned)hv[1] << 16) | hv[0];
            row[cp + 1] = ((unsigned)hv[3] << 16) | hv[2];
        }
    // same-wave LDS RAW: compiler orders via lgkmcnt; no barrier needed

    const int ow = 2 * (n0 + lane) + par;
    uint4* dst = reinterpret_cast<uint4*>(f0p + ((size_t)oh * WO + ow) * 32);
    const uint4* src = reinterpret_cast<const uint4*>(myep + lane * 20);
    #pragma unroll
    for (int u = 0; u < 4; ++u) dst[u] = src[u];
}

// ---------------------------------------------------------------------------
// kBC: FUSED stage B + stage C (R20 body). launch_bounds(256,8):
// VGPR 60 fits the 64 cap; LDS 19456 B x 8 = 155.6 KB <= 160 KiB.
// Doubles resident waves (16 -> 32/CU) in a latency-bound kernel.
// ---------------------------------------------------------------------------
__global__ __launch_bounds__(256, 8)
void kBC(const unsigned short* __restrict__ f0p, const uint4* __restrict__ wpB,
         const float* __restrict__ b1p, const uint4* __restrict__ wpC,
         const float* __restrict__ b2p, const float* __restrict__ flowp,
         float* __restrict__ out)
{
    __shared__ uint4 L4[134 * 7];           // fp16 plane, rows of 7 uint4 (56 ch)
    __shared__ float gm[2][128];            // per-m-half per-pixel min partials
    __shared__ float dvp[2][128];           // per-m-half softmax partials
    __shared__ float sxp[2][128];
    __shared__ float syp[2][128];
    unsigned* Lp = reinterpret_cast<unsigned*>(L4);

    // bijective XCD swizzle: 2048 blocks = 8 XCDs x 256 contiguous
    const int bid = ((blockIdx.x & 7) << 8) + (blockIdx.x >> 3);
    const int h   = bid >> 2;
    const int w0  = (bid & 3) << 7;

    const int tid  = threadIdx.x;
    const int wv   = tid >> 6;
    const int lane = tid & 63;
    const int col  = lane & 15;
    const int g    = lane >> 4;

    // ---- stage 1: f1 row h, cols w0-3 .. w0+140 (9 frags of 16) ------------
    const int nfr = (wv == 3) ? 3 : 2;
    const int fid0 = wv, fid1 = wv + 4, fid2 = 8;

    f32x4 acc1[3][4];
    #pragma unroll
    for (int fi = 0; fi < 3; ++fi)
        #pragma unroll
        for (int mf = 0; mf < 4; ++mf)
            acc1[fi][mf] = (f32x4){0.f, 0.f, 0.f, 0.f};

    #pragma unroll
    for (int t = 0; t < 7; ++t) {
        const int hr = h + t - 3;
        if ((unsigned)hr < (unsigned)HO) {
            FragH ah[4];
            #pragma unroll
            for (int mf = 0; mf < 4; ++mf)
                ah[mf].q = wpB[(t * 4 + mf) * 64 + lane];
            #pragma unroll
            for (int fi = 0; fi < 3; ++fi) {
                if (fi < nfr) {
                    const int f  = (fi == 0) ? fid0 : (fi == 1) ? fid1 : fid2;
                    const int wc = w0 - 3 + f * 16 + col;
                    const int wcc = min(max(wc, 0), WO - 1);
                    const bool valid = ((unsigned)wc < (unsigned)WO);
                    const size_t base = ((size_t)hr * WO + wcc) * 32 + g * 8;
                    FragH bf;
                    bf.q = *reinterpret_cast<const uint4*>(f0p + base);
                    if (!valid) bf.q = make_uint4(0u, 0u, 0u, 0u);
                    #pragma unroll
                    for (int mf = 0; mf < 4; ++mf)
                        acc1[fi][mf] = __builtin_amdgcn_mfma_f32_16x16x32_f16(ah[mf].v, bf.v, acc1[fi][mf], 0, 0, 0);
                }
            }
        }
    }

    // write f1 row into the FP16 plane; out-of-image columns store ZERO.
    #pragma unroll
    for (int fi = 0; fi < 3; ++fi) {
        if (fi < nfr) {
            const int f = (fi == 0) ? fid0 : (fi == 1) ? fid1 : fid2;
            const int q = f * 16 + col;
            const int wc = w0 - 3 + q;
            const bool vcol = ((unsigned)wc < (unsigned)WO);
            if (q < 134) {
                #pragma unroll
                for (int mf = 0; mf < 4; ++mf) {
                    if (mf < 3 || g < 2) {          // ch 56..63 don't exist
                        const int chb = mf * 16 + g * 4;
                        unsigned short hv[4];
                        #pragma unroll
                        for (int r = 0; r < 4; ++r) {
                            const float v = vcol ? (acc1[fi][mf][r] + b1p[chb + r]) : 0.f;
                            hv[r] = h_rne(v);
                        }
                        const int ip = mf * 8 + g * 2;
                        Lp[q * 28 + ip]     = ((unsigned)hv[1] << 16) | hv[0];
                        Lp[q * 28 + ip + 1] = ((unsigned)hv[3] << 16) | hv[2];
                    }
                }
            }
        }
    }
    __syncthreads();

    // ---- stage 2 (32x32x16 fp16): wave (wv_m, wv_n) = 32 ch x 64 px --------
    const int wv_m = wv >> 1;
    const int wv_n = wv & 1;
    const int lh   = lane >> 5;             // k-half selector
    const int p32  = lane & 31;             // pixel within 32-frag

    f32x16 acc2[2];
    #pragma unroll
    for (int nf = 0; nf < 2; ++nf)
        #pragma unroll
        for (int r = 0; r < 16; ++r)
            acc2[nf][r] = 0.f;

    #pragma unroll
    for (int cc = 0; cc < 25; ++cc) {       // cc=25 would be all-pad (kg 50,51)
        const int kg  = cc * 2 + lh;
        const int oct = (kg * 37) >> 8;     // kg/7 for kg<=51
        const int t   = kg - 7 * oct;
        FragH ah;
        ah.q = wpC[(cc * 2 + wv_m) * 64 + lane];
        const int bq = (wv_n * 64 + p32 + t) * 7 + oct;
        #pragma unroll
        for (int nf = 0; nf < 2; ++nf) {
            FragH bh;
            bh.q = L4[bq + nf * 224];       // +32 px * 7 uint4
            acc2[nf] = __builtin_amdgcn_mfma_f32_32x32x16_f16(ah.v, bh.v, acc2[nf], 0, 0, 0);
        }
    }

    // ---- epilogue (R12-validated): sq, 2-way min, flow average -------------
    // C/D: col(px) = lane&31, row(ch in 32) = (reg&3) + 8*(reg>>2) + 4*lh
    float bb2[16];
    #pragma unroll
    for (int reg = 0; reg < 16; ++reg) {
        const int ch = wv_m * 32 + lh * 4 + (reg & 3) + 8 * (reg >> 2);
        bb2[reg] = b2p[ch];
    }

    #pragma unroll
    for (int nf = 0; nf < 2; ++nf)
        #pragma unroll
        for (int reg = 0; reg < 16; ++reg) {
            const float fv = acc2[nf][reg] + bb2[reg];
            acc2[nf][reg] = fv * fv;
        }

    #pragma unroll
    for (int nf = 0; nf < 2; ++nf) {
        float m = acc2[nf][0];
        #pragma unroll
        for (int reg = 1; reg < 16; ++reg) m = fminf(m, acc2[nf][reg]);
        m = fminf(m, __shfl_xor(m, 32));
        if (lane < 32) gm[wv_m][wv_n * 64 + nf * 32 + lane] = m;
    }
    __syncthreads();

    float M2[2];
    #pragma unroll
    for (int nf = 0; nf < 2; ++nf) {
        const int px = wv_n * 64 + nf * 32 + p32;
        M2[nf] = fminf(gm[0][px], gm[1][px]);
    }

    const float* fpx = flowp + (size_t)h * FP_W + (w0 + wv_n * 64 + p32);
    const float* fpy = fpx + (size_t)FP_W * FP_W;
    float dv[2] = {0.f, 0.f}, sx[2] = {0.f, 0.f}, sy[2] = {0.f, 0.f};

    #pragma unroll
    for (int reg = 0; reg < 16; ++reg) {
        const int ch = wv_m * 32 + lh * 4 + (reg & 3) + 8 * (reg >> 2);
        int ki = (ch * 37) >> 8;            // floor(ch/7) for ch<64
        int kj = ch - 7 * ki;
        ki = min(ki, 6);                    // pad channels: d==0, clamp for safety
        kj = min(kj, 6);
        const int off = ki * FP_W + kj;
        #pragma unroll
        for (int nf = 0; nf < 2; ++nf) {
            const float d = __expf(M2[nf] - acc2[nf][reg]);
            dv[nf] += d;
            sx[nf] += d * fpx[off + nf * 32];
            sy[nf] += d * fpy[off + nf * 32];
        }
    }

    #pragma unroll
    for (int nf = 0; nf < 2; ++nf) {
        float d = dv[nf], x = sx[nf], y = sy[nf];
        d += __shfl_xor(d, 32);  x += __shfl_xor(x, 32);  y += __shfl_xor(y, 32);
        if (lane < 32) {
            const int px = wv_n * 64 + nf * 32 + lane;
            dvp[wv_m][px] = d;
            sxp[wv_m][px] = x;
            syp[wv_m][px] = y;
        }
    }
    __syncthreads();

    if (tid < 128) {
        const float D = dvp[0][tid] + dvp[1][tid];
        const float X = sxp[0][tid] + sxp[1][tid];
        const float Y = syp[0][tid] + syp[1][tid];
        const int w = w0 + tid;
        out[(size_t)h * WO + w]                   = X / D;
        out[(size_t)HO * WO + (size_t)h * WO + w] = Y / D;
    }
}

// ---------------------------------------------------------------------------
extern "C" void kernel_launch(void* const* d_in, const int* in_sizes, int n_in,
                              void* d_out, int out_size, void* d_ws, size_t ws_size,
                              hipStream_t stream) {
    const float* reg_feat = (const float*)d_in[0];
    const float* flow     = (const float*)d_in[1];
    const float* wt       = (const float*)d_in[2];
    const float* bt       = (const float*)d_in[3];
    const float* w1       = (const float*)d_in[4];
    const float* b1       = (const float*)d_in[5];
    const float* w2       = (const float*)d_in[6];
    const float* b2       = (const float*)d_in[7];
    float* out = (float*)d_out;
    (void)in_sizes; (void)n_in; (void)out_size; (void)ws_size;

    float*          ws    = (float*)d_ws;
    uint4*          wpC   = (uint4*)(ws + OFF_WPC);
    float*          b2p   = ws + OFF_B2P;
    uint4*          wpB   = (uint4*)(ws + OFF_WPB);
    float*          b1p   = ws + OFF_B1P;
    uint4*          wpA   = (uint4*)(ws + OFF_WPA);
    unsigned short* f0p   = (unsigned short*)(ws + OFF_F0);
    unsigned short* xp    = (unsigned short*)(ws + OFF_XP);
    float*          flowp = ws + OFF_FLP;

    repack<<<26, 256, 0, stream>>>(wt, w1, b1, w2, b2, wpA, wpB, b1p, wpC, b2p);

    const int padBlocks = XP_W + (2 * FP_W * FP_W + 255) / 256;
    for (int b = 0; b < 4; ++b) {
        const float* xb  = reg_feat + (size_t)b * CI * HI * WI;
        const float* flb = flow     + (size_t)b * 2 * HO * WO;
        float*       ob  = out      + (size_t)b * 2 * HO * WO;
        kPP<<<padBlocks, 256, 0, stream>>>(xb, flb, xp, flowp);
        kA<<<1024, 256, 0, stream>>>(xp, wpA, bt, f0p);
        kBC<<<2048, 256, 0, stream>>>(f0p, wpB, b1p, wpC, b2p, flowp, ob);
    }
}

// Round 22
// 257.205 us; speedup vs baseline: 1.4698x; 1.4698x over previous
//
#include <hip/hip_runtime.h>
#include <hip/hip_fp16.h>

constexpr int HI = 256, WI = 256;   // reg_feat spatial
constexpr int HO = 512, WO = 512;   // upsampled spatial
constexpr int CI = 32;              // feat channels
constexpr int CK = 49;              // 7x7 unfold channels

// ---- ws layout (float offsets) --------------------------------------------
constexpr size_t OFF_WPC = 0;                         // w2 fp16 32x32: 26*2*64 uint4 = 13312 f32
constexpr size_t OFF_B2P = 13312;                     // padded b2 [64]
constexpr size_t OFF_WPB = 13376;                     // w1 fp16: 7*4*64 uint4 = 7168 f32
constexpr size_t OFF_B1P = 20544;                     // padded b1 [64]
constexpr size_t OFF_WPA = 20608;                     // wt fp16: 4*4*2*64 uint4 = 8192 f32
constexpr size_t OFF_F0  = 28800;                     // f0p fp16 [512][512][32]
constexpr size_t OFF_XP  = OFF_F0 + (size_t)HO * WO * CI / 2;     // xp fp16 [258][258][32]
constexpr size_t OFF_FLP = OFF_XP + (size_t)258 * 258 * 32 / 2;   // flowp f32 [2][518][518]

constexpr int FP_W = 518;            // padded flow row (512 + 3 + 3)
constexpr int XP_W = 258;            // padded x row (256 + 1 + 1)

using f16x8  = __attribute__((ext_vector_type(8))) _Float16;
using f32x4  = __attribute__((ext_vector_type(4))) float;
using f32x16 = __attribute__((ext_vector_type(16))) float;

__device__ inline unsigned short h_rne(float x) {      // fp32 -> fp16 bits (RNE)
    return __half_as_ushort(__float2half(x));
}

union FragH { uint4 q; f16x8 v; };

// ---------------------------------------------------------------------------
// kPP: x -> single fp16 plane xp [258][258][32] (zero border); flow -> flowp.
// ---------------------------------------------------------------------------
__global__ void kPP(const float* __restrict__ x, const float* __restrict__ flow,
                    unsigned short* __restrict__ xp, float* __restrict__ flowp)
{
    const int bid = blockIdx.x;
    if (bid < XP_W) {
        const int yp = bid;
        const int y  = yp - 1;
        for (int xpc = threadIdx.x; xpc < XP_W; xpc += 256) {
            const int xc = xpc - 1;
            uint4* dst = reinterpret_cast<uint4*>(xp + ((size_t)yp * XP_W + xpc) * 32);
            if ((unsigned)y < 256u && (unsigned)xc < 256u) {
                const float* src = x + y * 256 + xc;
                unsigned w[16];
                #pragma unroll
                for (int c2 = 0; c2 < 16; ++c2) {
                    const unsigned short h0 = h_rne(src[(size_t)(2 * c2) * 65536]);
                    const unsigned short h1 = h_rne(src[(size_t)(2 * c2 + 1) * 65536]);
                    w[c2] = ((unsigned)h1 << 16) | h0;
                }
                const uint4* q = reinterpret_cast<const uint4*>(w);
                #pragma unroll
                for (int r = 0; r < 4; ++r) dst[r] = q[r];
            } else {
                #pragma unroll
                for (int r = 0; r < 4; ++r) dst[r] = make_uint4(0u, 0u, 0u, 0u);
            }
        }
    } else {
        const int idx = (bid - XP_W) * 256 + threadIdx.x;
        if (idx >= 2 * FP_W * FP_W) return;
        const int p  = idx / (FP_W * FP_W);
        const int q  = idx - p * (FP_W * FP_W);
        const int hh = q / FP_W;
        const int ww = q - hh * FP_W;
        float v = 0.f;
        const int hs = hh - 3, wsx = ww - 3;
        if ((unsigned)hs < (unsigned)HO && (unsigned)wsx < (unsigned)WO)
            v = flow[p * (HO * WO) + hs * WO + wsx];
        flowp[idx] = v;
    }
}

// ---------------------------------------------------------------------------
// repack: wpA/wpB fp16 16x16; wpC fp16 32x32 encoding (R20, validated).
// ---------------------------------------------------------------------------
__global__ void repack(const float* __restrict__ wt,
                       const float* __restrict__ w1, const float* __restrict__ b1,
                       const float* __restrict__ w2, const float* __restrict__ b2,
                       uint4* __restrict__ wpA, uint4* __restrict__ wpB,
                       float* __restrict__ b1p, uint4* __restrict__ wpC,
                       float* __restrict__ b2p)
{
    const int j = blockIdx.x * 256 + threadIdx.x;
    if (j < 64) {
        b2p[j] = (j < CK) ? b2[j] : 1e18f;
        b1p[j] = (j < CK) ? b1[j] : 0.f;
    }
    if (j < 4 * 4 * 2 * 64) {               // kA fp16
        const int lane = j & 63;
        const int mf   = (j >> 6) & 1;
        const int tap  = (j >> 7) & 3;
        const int cls  = j >> 9;
        const int ohpar = cls >> 1, par = cls & 1;
        const int a = tap >> 1, d = tap & 1;
        const int kh = (ohpar ? 0 : 1) + 2 * a;
        const int kw = (par ? 0 : 1) + 2 * d;
        const int o = mf * 16 + (lane & 15);
        unsigned short b[8];
        #pragma unroll
        for (int jj = 0; jj < 8; ++jj) {
            const int i = (lane >> 4) * 8 + jj;
            b[jj] = h_rne(wt[((i * 32 + o) * 4 + kh) * 4 + kw]);
        }
        uint4 q;
        q.x = ((unsigned)b[1] << 16) | b[0];
        q.y = ((unsigned)b[3] << 16) | b[2];
        q.z = ((unsigned)b[5] << 16) | b[4];
        q.w = ((unsigned)b[7] << 16) | b[6];
        wpA[((cls * 4 + tap) * 2 + mf) * 64 + lane] = q;
    }
    if (j < 7 * 4 * 64) {                   // stage-1 fp16: chunk t, k = i
        const int lane = j & 63;
        const int mf   = (j >> 6) & 3;
        const int t    = j >> 8;
        const int o = mf * 16 + (lane & 15);
        unsigned short b[8];
        #pragma unroll
        for (int jj = 0; jj < 8; ++jj) {
            const int i = (lane >> 4) * 8 + jj;
            b[jj] = h_rne((o < CK) ? w1[o * 224 + i * 7 + t] : 0.f);
        }
        uint4 q;
        q.x = ((unsigned)b[1] << 16) | b[0];
        q.y = ((unsigned)b[3] << 16) | b[2];
        q.z = ((unsigned)b[5] << 16) | b[4];
        q.w = ((unsigned)b[7] << 16) | b[6];
        wpB[(t * 4 + mf) * 64 + lane] = q;
    }
    if (j < 26 * 2 * 64) {                  // stage-2 fp16, 32x32 encoding
        const int lane = j & 63;
        const int m    = (j >> 6) & 1;
        const int cc   = j >> 7;
        const int o    = m * 32 + (lane & 31);
        const int kg   = cc * 2 + (lane >> 5);
        const int oct  = kg / 7;
        const int t    = kg - 7 * oct;
        unsigned short b[8];
        #pragma unroll
        for (int jj = 0; jj < 8; ++jj) {
            const int i = oct * 8 + jj;
            float v = 0.f;
            if (kg < CK && o < CK && i < CK) v = w2[o * 343 + i * 7 + t];
            b[jj] = h_rne(v);
        }
        uint4 q;
        q.x = ((unsigned)b[1] << 16) | b[0];
        q.y = ((unsigned)b[3] << 16) | b[2];
        q.z = ((unsigned)b[5] << 16) | b[4];
        q.w = ((unsigned)b[7] << 16) | b[6];
        wpC[(cc * 2 + m) * 64 + lane] = q;
    }
}

// ---------------------------------------------------------------------------
// kA: ConvTranspose2d via fp16 MFMA (R19/R20 body, launch_bounds(256,4) —
// 8 blocks/CU spills: R21 measured VGPR cap 32 + 96MB scratch writes).
// ---------------------------------------------------------------------------
__global__ __launch_bounds__(256, 4)
void kA(const unsigned short* __restrict__ xp, const uint4* __restrict__ wpA,
        const float* __restrict__ bt, unsigned short* __restrict__ f0p)
{
    __shared__ unsigned ep[4][64 * 20];     // [px][16 u32 fp16-pairs + 4 pad]

    const int tid  = threadIdx.x;
    const int oh   = blockIdx.x >> 1;
    const int half = blockIdx.x & 1;
    const int wv   = tid >> 6;
    const int lane = tid & 63;
    const int col  = lane & 15;
    const int g    = lane >> 4;
    const int par  = wv >> 1;
    const int n0   = half * 128 + (wv & 1) * 64;

    const int ohpar = oh & 1;
    const int kh0   = ohpar ? 0 : 1;
    const int ihA   = (oh + 1 - kh0) >> 1;
    const int cls   = ohpar * 2 + par;
    const int ioff  = par ? 2 : 1;

    f32x4 acc[2][4];
    #pragma unroll
    for (int mf = 0; mf < 2; ++mf)
        #pragma unroll
        for (int nf = 0; nf < 4; ++nf)
            acc[mf][nf] = (f32x4){0.f, 0.f, 0.f, 0.f};

    #pragma unroll
    for (int a = 0; a < 2; ++a) {
        const int rowbase = (ihA + 1 - a) * XP_W;
        #pragma unroll
        for (int d = 0; d < 2; ++d) {
            FragH B[4];
            #pragma unroll
            for (int nf = 0; nf < 4; ++nf) {
                const size_t base =
                    ((size_t)(rowbase + n0 + nf * 16 + col + ioff - d)) * 32 + g * 8;
                B[nf].q = *reinterpret_cast<const uint4*>(xp + base);
            }
            const int tap = a * 2 + d;
            #pragma unroll
            for (int mf = 0; mf < 2; ++mf) {
                FragH ah;
                ah.q = wpA[((cls * 4 + tap) * 2 + mf) * 64 + lane];
                #pragma unroll
                for (int nf = 0; nf < 4; ++nf)
                    acc[mf][nf] = __builtin_amdgcn_mfma_f32_16x16x32_f16(ah.v, B[nf].v, acc[mf][nf], 0, 0, 0);
            }
        }
    }

    unsigned* myep = ep[wv];
    #pragma unroll
    for (int mf = 0; mf < 2; ++mf)
        #pragma unroll
        for (int nf = 0; nf < 4; ++nf) {
            unsigned short hv[4];
            #pragma unroll
            for (int r = 0; r < 4; ++r) {
                const int ch = mf * 16 + g * 4 + r;
                hv[r] = h_rne(acc[mf][nf][r] + bt[ch]);
            }
            unsigned* row = myep + (nf * 16 + col) * 20;
            const int cp = mf * 8 + g * 2;
            row[cp]     = ((unsigned)hv[1] << 16) | hv[0];
            row[cp + 1] = ((unsigned)hv[3] << 16) | hv[2];
        }
    // same-wave LDS RAW: compiler orders via lgkmcnt; no barrier needed

    const int ow = 2 * (n0 + lane) + par;
    uint4* dst = reinterpret_cast<uint4*>(f0p + ((size_t)oh * WO + ow) * 32);
    const uint4* src = reinterpret_cast<const uint4*>(myep + lane * 20);
    #pragma unroll
    for (int u = 0; u < 4; ++u) dst[u] = src[u];
}

// ---------------------------------------------------------------------------
// kBC: FUSED stage B + stage C (R20 body, launch_bounds(256,4)).
// Stage 1: fp16 16x16; stage 2: 32x32x16 fp16, wave (wv_m,wv_n) = 32ch x 64px.
// ---------------------------------------------------------------------------
__global__ __launch_bounds__(256, 4)
void kBC(const unsigned short* __restrict__ f0p, const uint4* __restrict__ wpB,
         const float* __restrict__ b1p, const uint4* __restrict__ wpC,
         const float* __restrict__ b2p, const float* __restrict__ flowp,
         float* __restrict__ out)
{
    __shared__ uint4 L4[134 * 7];           // fp16 plane, rows of 7 uint4 (56 ch)
    __shared__ float gm[2][128];            // per-m-half per-pixel min partials
    __shared__ float dvp[2][128];           // per-m-half softmax partials
    __shared__ float sxp[2][128];
    __shared__ float syp[2][128];
    unsigned* Lp = reinterpret_cast<unsigned*>(L4);

    // bijective XCD swizzle: 2048 blocks = 8 XCDs x 256 contiguous
    const int bid = ((blockIdx.x & 7) << 8) + (blockIdx.x >> 3);
    const int h   = bid >> 2;
    const int w0  = (bid & 3) << 7;

    const int tid  = threadIdx.x;
    const int wv   = tid >> 6;
    const int lane = tid & 63;
    const int col  = lane & 15;
    const int g    = lane >> 4;

    // ---- stage 1: f1 row h, cols w0-3 .. w0+140 (9 frags of 16) ------------
    const int nfr = (wv == 3) ? 3 : 2;
    const int fid0 = wv, fid1 = wv + 4, fid2 = 8;

    f32x4 acc1[3][4];
    #pragma unroll
    for (int fi = 0; fi < 3; ++fi)
        #pragma unroll
        for (int mf = 0; mf < 4; ++mf)
            acc1[fi][mf] = (f32x4){0.f, 0.f, 0.f, 0.f};

    #pragma unroll
    for (int t = 0; t < 7; ++t) {
        const int hr = h + t - 3;
        if ((unsigned)hr < (unsigned)HO) {
            FragH ah[4];
            #pragma unroll
            for (int mf = 0; mf < 4; ++mf)
                ah[mf].q = wpB[(t * 4 + mf) * 64 + lane];
            #pragma unroll
            for (int fi = 0; fi < 3; ++fi) {
                if (fi < nfr) {
                    const int f  = (fi == 0) ? fid0 : (fi == 1) ? fid1 : fid2;
                    const int wc = w0 - 3 + f * 16 + col;
                    const int wcc = min(max(wc, 0), WO - 1);
                    const bool valid = ((unsigned)wc < (unsigned)WO);
                    const size_t base = ((size_t)hr * WO + wcc) * 32 + g * 8;
                    FragH bf;
                    bf.q = *reinterpret_cast<const uint4*>(f0p + base);
                    if (!valid) bf.q = make_uint4(0u, 0u, 0u, 0u);
                    #pragma unroll
                    for (int mf = 0; mf < 4; ++mf)
                        acc1[fi][mf] = __builtin_amdgcn_mfma_f32_16x16x32_f16(ah[mf].v, bf.v, acc1[fi][mf], 0, 0, 0);
                }
            }
        }
    }

    // write f1 row into the FP16 plane; out-of-image columns store ZERO.
    #pragma unroll
    for (int fi = 0; fi < 3; ++fi) {
        if (fi < nfr) {
            const int f = (fi == 0) ? fid0 : (fi == 1) ? fid1 : fid2;
            const int q = f * 16 + col;
            const int wc = w0 - 3 + q;
            const bool vcol = ((unsigned)wc < (unsigned)WO);
            if (q < 134) {
                #pragma unroll
                for (int mf = 0; mf < 4; ++mf) {
                    if (mf < 3 || g < 2) {          // ch 56..63 don't exist
                        const int chb = mf * 16 + g * 4;
                        unsigned short hv[4];
                        #pragma unroll
                        for (int r = 0; r < 4; ++r) {
                            const float v = vcol ? (acc1[fi][mf][r] + b1p[chb + r]) : 0.f;
                            hv[r] = h_rne(v);
                        }
                        const int ip = mf * 8 + g * 2;
                        Lp[q * 28 + ip]     = ((unsigned)hv[1] << 16) | hv[0];
                        Lp[q * 28 + ip + 1] = ((unsigned)hv[3] << 16) | hv[2];
                    }
                }
            }
        }
    }
    __syncthreads();

    // ---- stage 2 (32x32x16 fp16): wave (wv_m, wv_n) = 32 ch x 64 px --------
    const int wv_m = wv >> 1;
    const int wv_n = wv & 1;
    const int lh   = lane >> 5;             // k-half selector
    const int p32  = lane & 31;             // pixel within 32-frag

    f32x16 acc2[2];
    #pragma unroll
    for (int nf = 0; nf < 2; ++nf)
        #pragma unroll
        for (int r = 0; r < 16; ++r)
            acc2[nf][r] = 0.f;

    #pragma unroll
    for (int cc = 0; cc < 25; ++cc) {       // cc=25 would be all-pad (kg 50,51)
        const int kg  = cc * 2 + lh;
        const int oct = (kg * 37) >> 8;     // kg/7 for kg<=51
        const int t   = kg - 7 * oct;
        FragH ah;
        ah.q = wpC[(cc * 2 + wv_m) * 64 + lane];
        const int bq = (wv_n * 64 + p32 + t) * 7 + oct;
        #pragma unroll
        for (int nf = 0; nf < 2; ++nf) {
            FragH bh;
            bh.q = L4[bq + nf * 224];       // +32 px * 7 uint4
            acc2[nf] = __builtin_amdgcn_mfma_f32_32x32x16_f16(ah.v, bh.v, acc2[nf], 0, 0, 0);
        }
    }

    // ---- epilogue (R12-validated): sq, 2-way min, flow average -------------
    // C/D: col(px) = lane&31, row(ch in 32) = (reg&3) + 8*(reg>>2) + 4*lh
    float bb2[16];
    #pragma unroll
    for (int reg = 0; reg < 16; ++reg) {
        const int ch = wv_m * 32 + lh * 4 + (reg & 3) + 8 * (reg >> 2);
        bb2[reg] = b2p[ch];
    }

    #pragma unroll
    for (int nf = 0; nf < 2; ++nf)
        #pragma unroll
        for (int reg = 0; reg < 16; ++reg) {
            const float fv = acc2[nf][reg] + bb2[reg];
            acc2[nf][reg] = fv * fv;
        }

    #pragma unroll
    for (int nf = 0; nf < 2; ++nf) {
        float m = acc2[nf][0];
        #pragma unroll
        for (int reg = 1; reg < 16; ++reg) m = fminf(m, acc2[nf][reg]);
        m = fminf(m, __shfl_xor(m, 32));
        if (lane < 32) gm[wv_m][wv_n * 64 + nf * 32 + lane] = m;
    }
    __syncthreads();

    float M2[2];
    #pragma unroll
    for (int nf = 0; nf < 2; ++nf) {
        const int px = wv_n * 64 + nf * 32 + p32;
        M2[nf] = fminf(gm[0][px], gm[1][px]);
    }

    const float* fpx = flowp + (size_t)h * FP_W + (w0 + wv_n * 64 + p32);
    const float* fpy = fpx + (size_t)FP_W * FP_W;
    float dv[2] = {0.f, 0.f}, sx[2] = {0.f, 0.f}, sy[2] = {0.f, 0.f};

    #pragma unroll
    for (int reg = 0; reg < 16; ++reg) {
        const int ch = wv_m * 32 + lh * 4 + (reg & 3) + 8 * (reg >> 2);
        int ki = (ch * 37) >> 8;            // floor(ch/7) for ch<64
        int kj = ch - 7 * ki;
        ki = min(ki, 6);                    // pad channels: d==0, clamp for safety
        kj = min(kj, 6);
        const int off = ki * FP_W + kj;
        #pragma unroll
        for (int nf = 0; nf < 2; ++nf) {
            const float d = __expf(M2[nf] - acc2[nf][reg]);
            dv[nf] += d;
            sx[nf] += d * fpx[off + nf * 32];
            sy[nf] += d * fpy[off + nf * 32];
        }
    }

    #pragma unroll
    for (int nf = 0; nf < 2; ++nf) {
        float d = dv[nf], x = sx[nf], y = sy[nf];
        d += __shfl_xor(d, 32);  x += __shfl_xor(x, 32);  y += __shfl_xor(y, 32);
        if (lane < 32) {
            const int px = wv_n * 64 + nf * 32 + lane;
            dvp[wv_m][px] = d;
            sxp[wv_m][px] = x;
            syp[wv_m][px] = y;
        }
    }
    __syncthreads();

    if (tid < 128) {
        const float D = dvp[0][tid] + dvp[1][tid];
        const float X = sxp[0][tid] + sxp[1][tid];
        const float Y = syp[0][tid] + syp[1][tid];
        const int w = w0 + tid;
        out[(size_t)h * WO + w]                   = X / D;
        out[(size_t)HO * WO + (size_t)h * WO + w] = Y / D;
    }
}

// ---------------------------------------------------------------------------
extern "C" void kernel_launch(void* const* d_in, const int* in_sizes, int n_in,
                              void* d_out, int out_size, void* d_ws, size_t ws_size,
                              hipStream_t stream) {
    const float* reg_feat = (const float*)d_in[0];
    const float* flow     = (const float*)d_in[1];
    const float* wt       = (const float*)d_in[2];
    const float* bt       = (const float*)d_in[3];
    const float* w1       = (const float*)d_in[4];
    const float* b1       = (const float*)d_in[5];
    const float* w2       = (const float*)d_in[6];
    const float* b2       = (const float*)d_in[7];
    float* out = (float*)d_out;
    (void)in_sizes; (void)n_in; (void)out_size; (void)ws_size;

    float*          ws    = (float*)d_ws;
    uint4*          wpC   = (uint4*)(ws + OFF_WPC);
    float*          b2p   = ws + OFF_B2P;
    uint4*          wpB   = (uint4*)(ws + OFF_WPB);
    float*          b1p   = ws + OFF_B1P;
    uint4*          wpA   = (uint4*)(ws + OFF_WPA);
    unsigned short* f0p   = (unsigned short*)(ws + OFF_F0);
    unsigned short* xp    = (unsigned short*)(ws + OFF_XP);
    float*          flowp = ws + OFF_FLP;

    repack<<<26, 256, 0, stream>>>(wt, w1, b1, w2, b2, wpA, wpB, b1p, wpC, b2p);

    const int padBlocks = XP_W + (2 * FP_W * FP_W + 255) / 256;
    for (int b = 0; b < 4; ++b) {
        const float* xb  = reg_feat + (size_t)b * CI * HI * WI;
        const float* flb = flow     + (size_t)b * 2 * HO * WO;
        float*       ob  = out      + (size_t)b * 2 * HO * WO;
        kPP<<<padBlocks, 256, 0, stream>>>(xb, flb, xp, flowp);
        kA<<<1024, 256, 0, stream>>>(xp, wpA, bt, f0p);
        kBC<<<2048, 256, 0, stream>>>(f0p, wpB, b1p, wpC, b2p, flowp, ob);
    }
}

// Round 23
// 228.569 us; speedup vs baseline: 1.6540x; 1.1253x over previous
//
#include <hip/hip_runtime.h>
#include <hip/hip_fp16.h>

constexpr int HI = 256, WI = 256;   // reg_feat spatial
constexpr int HO = 512, WO = 512;   // upsampled spatial
constexpr int CI = 32;              // feat channels
constexpr int CK = 49;              // 7x7 unfold channels

constexpr int FP_W = 518;            // padded flow row (512 + 3 + 3)
constexpr int XP_W = 258;            // padded x row (256 + 1 + 1)

// ---- per-batch buffer strides ----------------------------------------------
constexpr size_t F0_US  = (size_t)HO * WO * CI;        // f0p ushorts/batch  (8.39M)
constexpr size_t XP_US  = (size_t)XP_W * XP_W * 32;    // xp  ushorts/batch  (2.13M)
constexpr size_t FLP_F  = (size_t)2 * FP_W * FP_W;     // flowp f32/batch    (0.54M)

// ---- ws layout (f32 word offsets) ------------------------------------------
constexpr size_t OFF_WPC = 0;                          // w2 fp16 32x32: 13312 f32
constexpr size_t OFF_B2P = 13312;
constexpr size_t OFF_WPB = 13376;                      // w1 fp16: 7168 f32
constexpr size_t OFF_B1P = 20544;
constexpr size_t OFF_WPA = 20608;                      // wt fp16: 8192 f32
constexpr size_t OFF_F0  = 28800;                      // f0p[2 batches]
constexpr size_t OFF_XP  = OFF_F0 + 2 * (F0_US / 2);   // xp[2 batches]
constexpr size_t OFF_FLP = OFF_XP + 2 * (XP_US / 2);   // flowp[2 batches]
// total ~11.6M f32 = 46.5 MB (<= 85 MB confirmed-working ws floor)

using f16x8  = __attribute__((ext_vector_type(8))) _Float16;
using f32x4  = __attribute__((ext_vector_type(4))) float;
using f32x16 = __attribute__((ext_vector_type(16))) float;

__device__ inline unsigned short h_rne(float x) {      // fp32 -> fp16 bits (RNE)
    return __half_as_ushort(__float2half(x));
}

union FragH { uint4 q; f16x8 v; };

// ---------------------------------------------------------------------------
// kPP: x -> fp16 plane xp (zero border); flow -> flowp. blockIdx.y = batch
// within the pair (per-batch pointer strides).
// ---------------------------------------------------------------------------
__global__ void kPP(const float* __restrict__ x, const float* __restrict__ flow,
                    unsigned short* __restrict__ xp, float* __restrict__ flowp)
{
    const int by = blockIdx.y;
    x     += (size_t)by * CI * HI * WI;
    flow  += (size_t)by * 2 * HO * WO;
    xp    += (size_t)by * XP_US;
    flowp += (size_t)by * FLP_F;

    const int bid = blockIdx.x;
    if (bid < XP_W) {
        const int yp = bid;
        const int y  = yp - 1;
        for (int xpc = threadIdx.x; xpc < XP_W; xpc += 256) {
            const int xc = xpc - 1;
            uint4* dst = reinterpret_cast<uint4*>(xp + ((size_t)yp * XP_W + xpc) * 32);
            if ((unsigned)y < 256u && (unsigned)xc < 256u) {
                const float* src = x + y * 256 + xc;
                unsigned w[16];
                #pragma unroll
                for (int c2 = 0; c2 < 16; ++c2) {
                    const unsigned short h0 = h_rne(src[(size_t)(2 * c2) * 65536]);
                    const unsigned short h1 = h_rne(src[(size_t)(2 * c2 + 1) * 65536]);
                    w[c2] = ((unsigned)h1 << 16) | h0;
                }
                const uint4* q = reinterpret_cast<const uint4*>(w);
                #pragma unroll
                for (int r = 0; r < 4; ++r) dst[r] = q[r];
            } else {
                #pragma unroll
                for (int r = 0; r < 4; ++r) dst[r] = make_uint4(0u, 0u, 0u, 0u);
            }
        }
    } else {
        const int idx = (bid - XP_W) * 256 + threadIdx.x;
        if (idx >= 2 * FP_W * FP_W) return;
        const int p  = idx / (FP_W * FP_W);
        const int q  = idx - p * (FP_W * FP_W);
        const int hh = q / FP_W;
        const int ww = q - hh * FP_W;
        float v = 0.f;
        const int hs = hh - 3, wsx = ww - 3;
        if ((unsigned)hs < (unsigned)HO && (unsigned)wsx < (unsigned)WO)
            v = flow[p * (HO * WO) + hs * WO + wsx];
        flowp[idx] = v;
    }
}

// ---------------------------------------------------------------------------
// repack: wpA/wpB fp16 16x16; wpC fp16 32x32 encoding (R20, validated).
// ---------------------------------------------------------------------------
__global__ void repack(const float* __restrict__ wt,
                       const float* __restrict__ w1, const float* __restrict__ b1,
                       const float* __restrict__ w2, const float* __restrict__ b2,
                       uint4* __restrict__ wpA, uint4* __restrict__ wpB,
                       float* __restrict__ b1p, uint4* __restrict__ wpC,
                       float* __restrict__ b2p)
{
    const int j = blockIdx.x * 256 + threadIdx.x;
    if (j < 64) {
        b2p[j] = (j < CK) ? b2[j] : 1e18f;
        b1p[j] = (j < CK) ? b1[j] : 0.f;
    }
    if (j < 4 * 4 * 2 * 64) {               // kA fp16
        const int lane = j & 63;
        const int mf   = (j >> 6) & 1;
        const int tap  = (j >> 7) & 3;
        const int cls  = j >> 9;
        const int ohpar = cls >> 1, par = cls & 1;
        const int a = tap >> 1, d = tap & 1;
        const int kh = (ohpar ? 0 : 1) + 2 * a;
        const int kw = (par ? 0 : 1) + 2 * d;
        const int o = mf * 16 + (lane & 15);
        unsigned short b[8];
        #pragma unroll
        for (int jj = 0; jj < 8; ++jj) {
            const int i = (lane >> 4) * 8 + jj;
            b[jj] = h_rne(wt[((i * 32 + o) * 4 + kh) * 4 + kw]);
        }
        uint4 q;
        q.x = ((unsigned)b[1] << 16) | b[0];
        q.y = ((unsigned)b[3] << 16) | b[2];
        q.z = ((unsigned)b[5] << 16) | b[4];
        q.w = ((unsigned)b[7] << 16) | b[6];
        wpA[((cls * 4 + tap) * 2 + mf) * 64 + lane] = q;
    }
    if (j < 7 * 4 * 64) {                   // stage-1 fp16: chunk t, k = i
        const int lane = j & 63;
        const int mf   = (j >> 6) & 3;
        const int t    = j >> 8;
        const int o = mf * 16 + (lane & 15);
        unsigned short b[8];
        #pragma unroll
        for (int jj = 0; jj < 8; ++jj) {
            const int i = (lane >> 4) * 8 + jj;
            b[jj] = h_rne((o < CK) ? w1[o * 224 + i * 7 + t] : 0.f);
        }
        uint4 q;
        q.x = ((unsigned)b[1] << 16) | b[0];
        q.y = ((unsigned)b[3] << 16) | b[2];
        q.z = ((unsigned)b[5] << 16) | b[4];
        q.w = ((unsigned)b[7] << 16) | b[6];
        wpB[(t * 4 + mf) * 64 + lane] = q;
    }
    if (j < 26 * 2 * 64) {                  // stage-2 fp16, 32x32 encoding
        const int lane = j & 63;
        const int m    = (j >> 6) & 1;
        const int cc   = j >> 7;
        const int o    = m * 32 + (lane & 31);
        const int kg   = cc * 2 + (lane >> 5);
        const int oct  = kg / 7;
        const int t    = kg - 7 * oct;
        unsigned short b[8];
        #pragma unroll
        for (int jj = 0; jj < 8; ++jj) {
            const int i = oct * 8 + jj;
            float v = 0.f;
            if (kg < CK && o < CK && i < CK) v = w2[o * 343 + i * 7 + t];
            b[jj] = h_rne(v);
        }
        uint4 q;
        q.x = ((unsigned)b[1] << 16) | b[0];
        q.y = ((unsigned)b[3] << 16) | b[2];
        q.z = ((unsigned)b[5] << 16) | b[4];
        q.w = ((unsigned)b[7] << 16) | b[6];
        wpC[(cc * 2 + m) * 64 + lane] = q;
    }
}

// ---------------------------------------------------------------------------
// kA: ConvTranspose2d via fp16 MFMA (R20 body + blockIdx.y batch stride).
// ---------------------------------------------------------------------------
__global__ __launch_bounds__(256, 4)
void kA(const unsigned short* __restrict__ xp, const uint4* __restrict__ wpA,
        const float* __restrict__ bt, unsigned short* __restrict__ f0p)
{
    __shared__ unsigned ep[4][64 * 20];     // [px][16 u32 fp16-pairs + 4 pad]

    const int by = blockIdx.y;
    xp  += (size_t)by * XP_US;
    f0p += (size_t)by * F0_US;

    const int tid  = threadIdx.x;
    const int oh   = blockIdx.x >> 1;
    const int half = blockIdx.x & 1;
    const int wv   = tid >> 6;
    const int lane = tid & 63;
    const int col  = lane & 15;
    const int g    = lane >> 4;
    const int par  = wv >> 1;
    const int n0   = half * 128 + (wv & 1) * 64;

    const int ohpar = oh & 1;
    const int kh0   = ohpar ? 0 : 1;
    const int ihA   = (oh + 1 - kh0) >> 1;
    const int cls   = ohpar * 2 + par;
    const int ioff  = par ? 2 : 1;

    f32x4 acc[2][4];
    #pragma unroll
    for (int mf = 0; mf < 2; ++mf)
        #pragma unroll
        for (int nf = 0; nf < 4; ++nf)
            acc[mf][nf] = (f32x4){0.f, 0.f, 0.f, 0.f};

    #pragma unroll
    for (int a = 0; a < 2; ++a) {
        const int rowbase = (ihA + 1 - a) * XP_W;
        #pragma unroll
        for (int d = 0; d < 2; ++d) {
            FragH B[4];
            #pragma unroll
            for (int nf = 0; nf < 4; ++nf) {
                const size_t base =
                    ((size_t)(rowbase + n0 + nf * 16 + col + ioff - d)) * 32 + g * 8;
                B[nf].q = *reinterpret_cast<const uint4*>(xp + base);
            }
            const int tap = a * 2 + d;
            #pragma unroll
            for (int mf = 0; mf < 2; ++mf) {
                FragH ah;
                ah.q = wpA[((cls * 4 + tap) * 2 + mf) * 64 + lane];
                #pragma unroll
                for (int nf = 0; nf < 4; ++nf)
                    acc[mf][nf] = __builtin_amdgcn_mfma_f32_16x16x32_f16(ah.v, B[nf].v, acc[mf][nf], 0, 0, 0);
            }
        }
    }

    unsigned* myep = ep[wv];
    #pragma unroll
    for (int mf = 0; mf < 2; ++mf)
        #pragma unroll
        for (int nf = 0; nf < 4; ++nf) {
            unsigned short hv[4];
            #pragma unroll
            for (int r = 0; r < 4; ++r) {
                const int ch = mf * 16 + g * 4 + r;
                hv[r] = h_rne(acc[mf][nf][r] + bt[ch]);
            }
            unsigned* row = myep + (nf * 16 + col) * 20;
            const int cp = mf * 8 + g * 2;
            row[cp]     = ((unsigned)hv[1] << 16) | hv[0];
            row[cp + 1] = ((unsigned)hv[3] << 16) | hv[2];
        }
    // same-wave LDS RAW: compiler orders via lgkmcnt; no barrier needed

    const int ow = 2 * (n0 + lane) + par;
    uint4* dst = reinterpret_cast<uint4*>(f0p + ((size_t)oh * WO + ow) * 32);
    const uint4* src = reinterpret_cast<const uint4*>(myep + lane * 20);
    #pragma unroll
    for (int u = 0; u < 4; ++u) dst[u] = src[u];
}

// ---------------------------------------------------------------------------
// kBC: FUSED stage B + stage C (R20 body + blockIdx.y batch stride).
// ---------------------------------------------------------------------------
__global__ __launch_bounds__(256, 4)
void kBC(const unsigned short* __restrict__ f0p, const uint4* __restrict__ wpB,
         const float* __restrict__ b1p, const uint4* __restrict__ wpC,
         const float* __restrict__ b2p, const float* __restrict__ flowp,
         float* __restrict__ out)
{
    __shared__ uint4 L4[134 * 7];           // fp16 plane, rows of 7 uint4 (56 ch)
    __shared__ float gm[2][128];            // per-m-half per-pixel min partials
    __shared__ float dvp[2][128];           // per-m-half softmax partials
    __shared__ float sxp[2][128];
    __shared__ float syp[2][128];
    unsigned* Lp = reinterpret_cast<unsigned*>(L4);

    const int by = blockIdx.y;
    f0p   += (size_t)by * F0_US;
    flowp += (size_t)by * FLP_F;
    out   += (size_t)by * 2 * HO * WO;

    // bijective XCD swizzle: 2048 blocks = 8 XCDs x 256 contiguous
    const int bid = ((blockIdx.x & 7) << 8) + (blockIdx.x >> 3);
    const int h   = bid >> 2;
    const int w0  = (bid & 3) << 7;

    const int tid  = threadIdx.x;
    const int wv   = tid >> 6;
    const int lane = tid & 63;
    const int col  = lane & 15;
    const int g    = lane >> 4;

    // ---- stage 1: f1 row h, cols w0-3 .. w0+140 (9 frags of 16) ------------
    const int nfr = (wv == 3) ? 3 : 2;
    const int fid0 = wv, fid1 = wv + 4, fid2 = 8;

    f32x4 acc1[3][4];
    #pragma unroll
    for (int fi = 0; fi < 3; ++fi)
        #pragma unroll
        for (int mf = 0; mf < 4; ++mf)
            acc1[fi][mf] = (f32x4){0.f, 0.f, 0.f, 0.f};

    #pragma unroll
    for (int t = 0; t < 7; ++t) {
        const int hr = h + t - 3;
        if ((unsigned)hr < (unsigned)HO) {
            FragH ah[4];
            #pragma unroll
            for (int mf = 0; mf < 4; ++mf)
                ah[mf].q = wpB[(t * 4 + mf) * 64 + lane];
            #pragma unroll
            for (int fi = 0; fi < 3; ++fi) {
                if (fi < nfr) {
                    const int f  = (fi == 0) ? fid0 : (fi == 1) ? fid1 : fid2;
                    const int wc = w0 - 3 + f * 16 + col;
                    const int wcc = min(max(wc, 0), WO - 1);
                    const bool valid = ((unsigned)wc < (unsigned)WO);
                    const size_t base = ((size_t)hr * WO + wcc) * 32 + g * 8;
                    FragH bf;
                    bf.q = *reinterpret_cast<const uint4*>(f0p + base);
                    if (!valid) bf.q = make_uint4(0u, 0u, 0u, 0u);
                    #pragma unroll
                    for (int mf = 0; mf < 4; ++mf)
                        acc1[fi][mf] = __builtin_amdgcn_mfma_f32_16x16x32_f16(ah[mf].v, bf.v, acc1[fi][mf], 0, 0, 0);
                }
            }
        }
    }

    // write f1 row into the FP16 plane; out-of-image columns store ZERO.
    #pragma unroll
    for (int fi = 0; fi < 3; ++fi) {
        if (fi < nfr) {
            const int f = (fi == 0) ? fid0 : (fi == 1) ? fid1 : fid2;
            const int q = f * 16 + col;
            const int wc = w0 - 3 + q;
            const bool vcol = ((unsigned)wc < (unsigned)WO);
            if (q < 134) {
                #pragma unroll
                for (int mf = 0; mf < 4; ++mf) {
                    if (mf < 3 || g < 2) {          // ch 56..63 don't exist
                        const int chb = mf * 16 + g * 4;
                        unsigned short hv[4];
                        #pragma unroll
                        for (int r = 0; r < 4; ++r) {
                            const float v = vcol ? (acc1[fi][mf][r] + b1p[chb + r]) : 0.f;
                            hv[r] = h_rne(v);
                        }
                        const int ip = mf * 8 + g * 2;
                        Lp[q * 28 + ip]     = ((unsigned)hv[1] << 16) | hv[0];
                        Lp[q * 28 + ip + 1] = ((unsigned)hv[3] << 16) | hv[2];
                    }
                }
            }
        }
    }
    __syncthreads();

    // ---- stage 2 (32x32x16 fp16): wave (wv_m, wv_n) = 32 ch x 64 px --------
    const int wv_m = wv >> 1;
    const int wv_n = wv & 1;
    const int lh   = lane >> 5;             // k-half selector
    const int p32  = lane & 31;             // pixel within 32-frag

    f32x16 acc2[2];
    #pragma unroll
    for (int nf = 0; nf < 2; ++nf)
        #pragma unroll
        for (int r = 0; r < 16; ++r)
            acc2[nf][r] = 0.f;

    #pragma unroll
    for (int cc = 0; cc < 25; ++cc) {       // cc=25 would be all-pad (kg 50,51)
        const int kg  = cc * 2 + lh;
        const int oct = (kg * 37) >> 8;     // kg/7 for kg<=51
        const int t   = kg - 7 * oct;
        FragH ah;
        ah.q = wpC[(cc * 2 + wv_m) * 64 + lane];
        const int bq = (wv_n * 64 + p32 + t) * 7 + oct;
        #pragma unroll
        for (int nf = 0; nf < 2; ++nf) {
            FragH bh;
            bh.q = L4[bq + nf * 224];       // +32 px * 7 uint4
            acc2[nf] = __builtin_amdgcn_mfma_f32_32x32x16_f16(ah.v, bh.v, acc2[nf], 0, 0, 0);
        }
    }

    // ---- epilogue (R12-validated): sq, 2-way min, flow average -------------
    // C/D: col(px) = lane&31, row(ch in 32) = (reg&3) + 8*(reg>>2) + 4*lh
    float bb2[16];
    #pragma unroll
    for (int reg = 0; reg < 16; ++reg) {
        const int ch = wv_m * 32 + lh * 4 + (reg & 3) + 8 * (reg >> 2);
        bb2[reg] = b2p[ch];
    }

    #pragma unroll
    for (int nf = 0; nf < 2; ++nf)
        #pragma unroll
        for (int reg = 0; reg < 16; ++reg) {
            const float fv = acc2[nf][reg] + bb2[reg];
            acc2[nf][reg] = fv * fv;
        }

    #pragma unroll
    for (int nf = 0; nf < 2; ++nf) {
        float m = acc2[nf][0];
        #pragma unroll
        for (int reg = 1; reg < 16; ++reg) m = fminf(m, acc2[nf][reg]);
        m = fminf(m, __shfl_xor(m, 32));
        if (lane < 32) gm[wv_m][wv_n * 64 + nf * 32 + lane] = m;
    }
    __syncthreads();

    float M2[2];
    #pragma unroll
    for (int nf = 0; nf < 2; ++nf) {
        const int px = wv_n * 64 + nf * 32 + p32;
        M2[nf] = fminf(gm[0][px], gm[1][px]);
    }

    const float* fpx = flowp + (size_t)h * FP_W + (w0 + wv_n * 64 + p32);
    const float* fpy = fpx + (size_t)FP_W * FP_W;
    float dv[2] = {0.f, 0.f}, sx[2] = {0.f, 0.f}, sy[2] = {0.f, 0.f};

    #pragma unroll
    for (int reg = 0; reg < 16; ++reg) {
        const int ch = wv_m * 32 + lh * 4 + (reg & 3) + 8 * (reg >> 2);
        int ki = (ch * 37) >> 8;            // floor(ch/7) for ch<64
        int kj = ch - 7 * ki;
        ki = min(ki, 6);                    // pad channels: d==0, clamp for safety
        kj = min(kj, 6);
        const int off = ki * FP_W + kj;
        #pragma unroll
        for (int nf = 0; nf < 2; ++nf) {
            const float d = __expf(M2[nf] - acc2[nf][reg]);
            dv[nf] += d;
            sx[nf] += d * fpx[off + nf * 32];
            sy[nf] += d * fpy[off + nf * 32];
        }
    }

    #pragma unroll
    for (int nf = 0; nf < 2; ++nf) {
        float d = dv[nf], x = sx[nf], y = sy[nf];
        d += __shfl_xor(d, 32);  x += __shfl_xor(x, 32);  y += __shfl_xor(y, 32);
        if (lane < 32) {
            const int px = wv_n * 64 + nf * 32 + lane;
            dvp[wv_m][px] = d;
            sxp[wv_m][px] = x;
            syp[wv_m][px] = y;
        }
    }
    __syncthreads();

    if (tid < 128) {
        const float D = dvp[0][tid] + dvp[1][tid];
        const float X = sxp[0][tid] + sxp[1][tid];
        const float Y = syp[0][tid] + syp[1][tid];
        const int w = w0 + tid;
        out[(size_t)h * WO + w]                   = X / D;
        out[(size_t)HO * WO + (size_t)h * WO + w] = Y / D;
    }
}

// ---------------------------------------------------------------------------
extern "C" void kernel_launch(void* const* d_in, const int* in_sizes, int n_in,
                              void* d_out, int out_size, void* d_ws, size_t ws_size,
                              hipStream_t stream) {
    const float* reg_feat = (const float*)d_in[0];
    const float* flow     = (const float*)d_in[1];
    const float* wt       = (const float*)d_in[2];
    const float* bt       = (const float*)d_in[3];
    const float* w1       = (const float*)d_in[4];
    const float* b1       = (const float*)d_in[5];
    const float* w2       = (const float*)d_in[6];
    const float* b2       = (const float*)d_in[7];
    float* out = (float*)d_out;
    (void)in_sizes; (void)n_in; (void)out_size; (void)ws_size;

    float*          ws    = (float*)d_ws;
    uint4*          wpC   = (uint4*)(ws + OFF_WPC);
    float*          b2p   = ws + OFF_B2P;
    uint4*          wpB   = (uint4*)(ws + OFF_WPB);
    float*          b1p   = ws + OFF_B1P;
    uint4*          wpA   = (uint4*)(ws + OFF_WPA);
    unsigned short* f0p   = (unsigned short*)(ws + OFF_F0);
    unsigned short* xp    = (unsigned short*)(ws + OFF_XP);
    float*          flowp = ws + OFF_FLP;

    repack<<<26, 256, 0, stream>>>(wt, w1, b1, w2, b2, wpA, wpB, b1p, wpC, b2p);

    const int padBlocks = XP_W + (2 * FP_W * FP_W + 255) / 256;
    for (int pr = 0; pr < 2; ++pr) {
        const float* xb  = reg_feat + (size_t)pr * 2 * CI * HI * WI;
        const float* flb = flow     + (size_t)pr * 2 * 2 * HO * WO;
        float*       ob  = out      + (size_t)pr * 2 * 2 * HO * WO;
        kPP<<<dim3(padBlocks, 2), 256, 0, stream>>>(xb, flb, xp, flowp);
        kA <<<dim3(1024, 2),      256, 0, stream>>>(xp, wpA, bt, f0p);
        kBC<<<dim3(2048, 2),      256, 0, stream>>>(f0p, wpB, b1p, wpC, b2p, flowp, ob);
    }
}

// Round 24
// 208.105 us; speedup vs baseline: 1.8166x; 1.0983x over previous
//
#include <hip/hip_runtime.h>
#include <hip/hip_fp16.h>

constexpr int HI = 256, WI = 256;   // reg_feat spatial
constexpr int HO = 512, WO = 512;   // upsampled spatial
constexpr int CI = 32;              // feat channels
constexpr int CK = 49;              // 7x7 unfold channels

constexpr int FP_W = 518;            // padded flow row (512 + 3 + 3)
constexpr int XP_W = 258;            // padded x row (256 + 1 + 1)

// ---- per-batch buffer strides ----------------------------------------------
constexpr size_t F0_US  = (size_t)HO * WO * CI;        // f0p ushorts/batch  (8.39M)
constexpr size_t XP_US  = (size_t)XP_W * XP_W * 32;    // xp  ushorts/batch  (2.13M)
constexpr size_t FLP_F  = (size_t)2 * FP_W * FP_W;     // flowp f32/batch    (0.54M)

// ---- ws layout (f32 word offsets, weights header) --------------------------
constexpr size_t OFF_WPC = 0;                          // w2 fp16 32x32: 13312 f32
constexpr size_t OFF_B2P = 13312;
constexpr size_t OFF_WPB = 13376;                      // w1 fp16: 7168 f32
constexpr size_t OFF_B1P = 20544;
constexpr size_t OFF_WPA = 20608;                      // wt fp16: 8192 f32
constexpr size_t OFF_BUF = 28800;                      // batch buffers start here
constexpr size_t PB_F32  = F0_US / 2 + XP_US / 2 + FLP_F;  // per-batch f32 words

using f16x8  = __attribute__((ext_vector_type(8))) _Float16;
using f32x4  = __attribute__((ext_vector_type(4))) float;
using f32x16 = __attribute__((ext_vector_type(16))) float;

__device__ inline unsigned short h_rne(float x) {      // fp32 -> fp16 bits (RNE)
    return __half_as_ushort(__float2half(x));
}

union FragH { uint4 q; f16x8 v; };

// ---------------------------------------------------------------------------
// kPP: x -> fp16 plane xp (zero border); flow -> flowp. blockIdx.y = batch
// within the group (per-batch pointer strides).
// ---------------------------------------------------------------------------
__global__ void kPP(const float* __restrict__ x, const float* __restrict__ flow,
                    unsigned short* __restrict__ xp, float* __restrict__ flowp)
{
    const int by = blockIdx.y;
    x     += (size_t)by * CI * HI * WI;
    flow  += (size_t)by * 2 * HO * WO;
    xp    += (size_t)by * XP_US;
    flowp += (size_t)by * FLP_F;

    const int bid = blockIdx.x;
    if (bid < XP_W) {
        const int yp = bid;
        const int y  = yp - 1;
        for (int xpc = threadIdx.x; xpc < XP_W; xpc += 256) {
            const int xc = xpc - 1;
            uint4* dst = reinterpret_cast<uint4*>(xp + ((size_t)yp * XP_W + xpc) * 32);
            if ((unsigned)y < 256u && (unsigned)xc < 256u) {
                const float* src = x + y * 256 + xc;
                unsigned w[16];
                #pragma unroll
                for (int c2 = 0; c2 < 16; ++c2) {
                    const unsigned short h0 = h_rne(src[(size_t)(2 * c2) * 65536]);
                    const unsigned short h1 = h_rne(src[(size_t)(2 * c2 + 1) * 65536]);
                    w[c2] = ((unsigned)h1 << 16) | h0;
                }
                const uint4* q = reinterpret_cast<const uint4*>(w);
                #pragma unroll
                for (int r = 0; r < 4; ++r) dst[r] = q[r];
            } else {
                #pragma unroll
                for (int r = 0; r < 4; ++r) dst[r] = make_uint4(0u, 0u, 0u, 0u);
            }
        }
    } else {
        const int idx = (bid - XP_W) * 256 + threadIdx.x;
        if (idx >= 2 * FP_W * FP_W) return;
        const int p  = idx / (FP_W * FP_W);
        const int q  = idx - p * (FP_W * FP_W);
        const int hh = q / FP_W;
        const int ww = q - hh * FP_W;
        float v = 0.f;
        const int hs = hh - 3, wsx = ww - 3;
        if ((unsigned)hs < (unsigned)HO && (unsigned)wsx < (unsigned)WO)
            v = flow[p * (HO * WO) + hs * WO + wsx];
        flowp[idx] = v;
    }
}

// ---------------------------------------------------------------------------
// repack: wpA/wpB fp16 16x16; wpC fp16 32x32 encoding (R20, validated).
// ---------------------------------------------------------------------------
__global__ void repack(const float* __restrict__ wt,
                       const float* __restrict__ w1, const float* __restrict__ b1,
                       const float* __restrict__ w2, const float* __restrict__ b2,
                       uint4* __restrict__ wpA, uint4* __restrict__ wpB,
                       float* __restrict__ b1p, uint4* __restrict__ wpC,
                       float* __restrict__ b2p)
{
    const int j = blockIdx.x * 256 + threadIdx.x;
    if (j < 64) {
        b2p[j] = (j < CK) ? b2[j] : 1e18f;
        b1p[j] = (j < CK) ? b1[j] : 0.f;
    }
    if (j < 4 * 4 * 2 * 64) {               // kA fp16
        const int lane = j & 63;
        const int mf   = (j >> 6) & 1;
        const int tap  = (j >> 7) & 3;
        const int cls  = j >> 9;
        const int ohpar = cls >> 1, par = cls & 1;
        const int a = tap >> 1, d = tap & 1;
        const int kh = (ohpar ? 0 : 1) + 2 * a;
        const int kw = (par ? 0 : 1) + 2 * d;
        const int o = mf * 16 + (lane & 15);
        unsigned short b[8];
        #pragma unroll
        for (int jj = 0; jj < 8; ++jj) {
            const int i = (lane >> 4) * 8 + jj;
            b[jj] = h_rne(wt[((i * 32 + o) * 4 + kh) * 4 + kw]);
        }
        uint4 q;
        q.x = ((unsigned)b[1] << 16) | b[0];
        q.y = ((unsigned)b[3] << 16) | b[2];
        q.z = ((unsigned)b[5] << 16) | b[4];
        q.w = ((unsigned)b[7] << 16) | b[6];
        wpA[((cls * 4 + tap) * 2 + mf) * 64 + lane] = q;
    }
    if (j < 7 * 4 * 64) {                   // stage-1 fp16: chunk t, k = i
        const int lane = j & 63;
        const int mf   = (j >> 6) & 3;
        const int t    = j >> 8;
        const int o = mf * 16 + (lane & 15);
        unsigned short b[8];
        #pragma unroll
        for (int jj = 0; jj < 8; ++jj) {
            const int i = (lane >> 4) * 8 + jj;
            b[jj] = h_rne((o < CK) ? w1[o * 224 + i * 7 + t] : 0.f);
        }
        uint4 q;
        q.x = ((unsigned)b[1] << 16) | b[0];
        q.y = ((unsigned)b[3] << 16) | b[2];
        q.z = ((unsigned)b[5] << 16) | b[4];
        q.w = ((unsigned)b[7] << 16) | b[6];
        wpB[(t * 4 + mf) * 64 + lane] = q;
    }
    if (j < 26 * 2 * 64) {                  // stage-2 fp16, 32x32 encoding
        const int lane = j & 63;
        const int m    = (j >> 6) & 1;
        const int cc   = j >> 7;
        const int o    = m * 32 + (lane & 31);
        const int kg   = cc * 2 + (lane >> 5);
        const int oct  = kg / 7;
        const int t    = kg - 7 * oct;
        unsigned short b[8];
        #pragma unroll
        for (int jj = 0; jj < 8; ++jj) {
            const int i = oct * 8 + jj;
            float v = 0.f;
            if (kg < CK && o < CK && i < CK) v = w2[o * 343 + i * 7 + t];
            b[jj] = h_rne(v);
        }
        uint4 q;
        q.x = ((unsigned)b[1] << 16) | b[0];
        q.y = ((unsigned)b[3] << 16) | b[2];
        q.z = ((unsigned)b[5] << 16) | b[4];
        q.w = ((unsigned)b[7] << 16) | b[6];
        wpC[(cc * 2 + m) * 64 + lane] = q;
    }
}

// ---------------------------------------------------------------------------
// kA: ConvTranspose2d via fp16 MFMA (R23 body, blockIdx.y batch stride).
// ---------------------------------------------------------------------------
__global__ __launch_bounds__(256, 4)
void kA(const unsigned short* __restrict__ xp, const uint4* __restrict__ wpA,
        const float* __restrict__ bt, unsigned short* __restrict__ f0p)
{
    __shared__ unsigned ep[4][64 * 20];     // [px][16 u32 fp16-pairs + 4 pad]

    const int by = blockIdx.y;
    xp  += (size_t)by * XP_US;
    f0p += (size_t)by * F0_US;

    const int tid  = threadIdx.x;
    const int oh   = blockIdx.x >> 1;
    const int half = blockIdx.x & 1;
    const int wv   = tid >> 6;
    const int lane = tid & 63;
    const int col  = lane & 15;
    const int g    = lane >> 4;
    const int par  = wv >> 1;
    const int n0   = half * 128 + (wv & 1) * 64;

    const int ohpar = oh & 1;
    const int kh0   = ohpar ? 0 : 1;
    const int ihA   = (oh + 1 - kh0) >> 1;
    const int cls   = ohpar * 2 + par;
    const int ioff  = par ? 2 : 1;

    f32x4 acc[2][4];
    #pragma unroll
    for (int mf = 0; mf < 2; ++mf)
        #pragma unroll
        for (int nf = 0; nf < 4; ++nf)
            acc[mf][nf] = (f32x4){0.f, 0.f, 0.f, 0.f};

    #pragma unroll
    for (int a = 0; a < 2; ++a) {
        const int rowbase = (ihA + 1 - a) * XP_W;
        #pragma unroll
        for (int d = 0; d < 2; ++d) {
            FragH B[4];
            #pragma unroll
            for (int nf = 0; nf < 4; ++nf) {
                const size_t base =
                    ((size_t)(rowbase + n0 + nf * 16 + col + ioff - d)) * 32 + g * 8;
                B[nf].q = *reinterpret_cast<const uint4*>(xp + base);
            }
            const int tap = a * 2 + d;
            #pragma unroll
            for (int mf = 0; mf < 2; ++mf) {
                FragH ah;
                ah.q = wpA[((cls * 4 + tap) * 2 + mf) * 64 + lane];
                #pragma unroll
                for (int nf = 0; nf < 4; ++nf)
                    acc[mf][nf] = __builtin_amdgcn_mfma_f32_16x16x32_f16(ah.v, B[nf].v, acc[mf][nf], 0, 0, 0);
            }
        }
    }

    unsigned* myep = ep[wv];
    #pragma unroll
    for (int mf = 0; mf < 2; ++mf)
        #pragma unroll
        for (int nf = 0; nf < 4; ++nf) {
            unsigned short hv[4];
            #pragma unroll
            for (int r = 0; r < 4; ++r) {
                const int ch = mf * 16 + g * 4 + r;
                hv[r] = h_rne(acc[mf][nf][r] + bt[ch]);
            }
            unsigned* row = myep + (nf * 16 + col) * 20;
            const int cp = mf * 8 + g * 2;
            row[cp]     = ((unsigned)hv[1] << 16) | hv[0];
            row[cp + 1] = ((unsigned)hv[3] << 16) | hv[2];
        }
    // same-wave LDS RAW: compiler orders via lgkmcnt; no barrier needed

    const int ow = 2 * (n0 + lane) + par;
    uint4* dst = reinterpret_cast<uint4*>(f0p + ((size_t)oh * WO + ow) * 32);
    const uint4* src = reinterpret_cast<const uint4*>(myep + lane * 20);
    #pragma unroll
    for (int u = 0; u < 4; ++u) dst[u] = src[u];
}

// ---------------------------------------------------------------------------
// kBC: FUSED stage B + stage C (R23 body, blockIdx.y batch stride).
// ---------------------------------------------------------------------------
__global__ __launch_bounds__(256, 4)
void kBC(const unsigned short* __restrict__ f0p, const uint4* __restrict__ wpB,
         const float* __restrict__ b1p, const uint4* __restrict__ wpC,
         const float* __restrict__ b2p, const float* __restrict__ flowp,
         float* __restrict__ out)
{
    __shared__ uint4 L4[134 * 7];           // fp16 plane, rows of 7 uint4 (56 ch)
    __shared__ float gm[2][128];            // per-m-half per-pixel min partials
    __shared__ float dvp[2][128];           // per-m-half softmax partials
    __shared__ float sxp[2][128];
    __shared__ float syp[2][128];
    unsigned* Lp = reinterpret_cast<unsigned*>(L4);

    const int by = blockIdx.y;
    f0p   += (size_t)by * F0_US;
    flowp += (size_t)by * FLP_F;
    out   += (size_t)by * 2 * HO * WO;

    // bijective XCD swizzle: 2048 blocks = 8 XCDs x 256 contiguous
    const int bid = ((blockIdx.x & 7) << 8) + (blockIdx.x >> 3);
    const int h   = bid >> 2;
    const int w0  = (bid & 3) << 7;

    const int tid  = threadIdx.x;
    const int wv   = tid >> 6;
    const int lane = tid & 63;
    const int col  = lane & 15;
    const int g    = lane >> 4;

    // ---- stage 1: f1 row h, cols w0-3 .. w0+140 (9 frags of 16) ------------
    const int nfr = (wv == 3) ? 3 : 2;
    const int fid0 = wv, fid1 = wv + 4, fid2 = 8;

    f32x4 acc1[3][4];
    #pragma unroll
    for (int fi = 0; fi < 3; ++fi)
        #pragma unroll
        for (int mf = 0; mf < 4; ++mf)
            acc1[fi][mf] = (f32x4){0.f, 0.f, 0.f, 0.f};

    #pragma unroll
    for (int t = 0; t < 7; ++t) {
        const int hr = h + t - 3;
        if ((unsigned)hr < (unsigned)HO) {
            FragH ah[4];
            #pragma unroll
            for (int mf = 0; mf < 4; ++mf)
                ah[mf].q = wpB[(t * 4 + mf) * 64 + lane];
            #pragma unroll
            for (int fi = 0; fi < 3; ++fi) {
                if (fi < nfr) {
                    const int f  = (fi == 0) ? fid0 : (fi == 1) ? fid1 : fid2;
                    const int wc = w0 - 3 + f * 16 + col;
                    const int wcc = min(max(wc, 0), WO - 1);
                    const bool valid = ((unsigned)wc < (unsigned)WO);
                    const size_t base = ((size_t)hr * WO + wcc) * 32 + g * 8;
                    FragH bf;
                    bf.q = *reinterpret_cast<const uint4*>(f0p + base);
                    if (!valid) bf.q = make_uint4(0u, 0u, 0u, 0u);
                    #pragma unroll
                    for (int mf = 0; mf < 4; ++mf)
                        acc1[fi][mf] = __builtin_amdgcn_mfma_f32_16x16x32_f16(ah[mf].v, bf.v, acc1[fi][mf], 0, 0, 0);
                }
            }
        }
    }

    // write f1 row into the FP16 plane; out-of-image columns store ZERO.
    #pragma unroll
    for (int fi = 0; fi < 3; ++fi) {
        if (fi < nfr) {
            const int f = (fi == 0) ? fid0 : (fi == 1) ? fid1 : fid2;
            const int q = f * 16 + col;
            const int wc = w0 - 3 + q;
            const bool vcol = ((unsigned)wc < (unsigned)WO);
            if (q < 134) {
                #pragma unroll
                for (int mf = 0; mf < 4; ++mf) {
                    if (mf < 3 || g < 2) {          // ch 56..63 don't exist
                        const int chb = mf * 16 + g * 4;
                        unsigned short hv[4];
                        #pragma unroll
                        for (int r = 0; r < 4; ++r) {
                            const float v = vcol ? (acc1[fi][mf][r] + b1p[chb + r]) : 0.f;
                            hv[r] = h_rne(v);
                        }
                        const int ip = mf * 8 + g * 2;
                        Lp[q * 28 + ip]     = ((unsigned)hv[1] << 16) | hv[0];
                        Lp[q * 28 + ip + 1] = ((unsigned)hv[3] << 16) | hv[2];
                    }
                }
            }
        }
    }
    __syncthreads();

    // ---- stage 2 (32x32x16 fp16): wave (wv_m, wv_n) = 32 ch x 64 px --------
    const int wv_m = wv >> 1;
    const int wv_n = wv & 1;
    const int lh   = lane >> 5;             // k-half selector
    const int p32  = lane & 31;             // pixel within 32-frag

    f32x16 acc2[2];
    #pragma unroll
    for (int nf = 0; nf < 2; ++nf)
        #pragma unroll
        for (int r = 0; r < 16; ++r)
            acc2[nf][r] = 0.f;

    #pragma unroll
    for (int cc = 0; cc < 25; ++cc) {       // cc=25 would be all-pad (kg 50,51)
        const int kg  = cc * 2 + lh;
        const int oct = (kg * 37) >> 8;     // kg/7 for kg<=51
        const int t   = kg - 7 * oct;
        FragH ah;
        ah.q = wpC[(cc * 2 + wv_m) * 64 + lane];
        const int bq = (wv_n * 64 + p32 + t) * 7 + oct;
        #pragma unroll
        for (int nf = 0; nf < 2; ++nf) {
            FragH bh;
            bh.q = L4[bq + nf * 224];       // +32 px * 7 uint4
            acc2[nf] = __builtin_amdgcn_mfma_f32_32x32x16_f16(ah.v, bh.v, acc2[nf], 0, 0, 0);
        }
    }

    // ---- epilogue (R12-validated): sq, 2-way min, flow average -------------
    // C/D: col(px) = lane&31, row(ch in 32) = (reg&3) + 8*(reg>>2) + 4*lh
    float bb2[16];
    #pragma unroll
    for (int reg = 0; reg < 16; ++reg) {
        const int ch = wv_m * 32 + lh * 4 + (reg & 3) + 8 * (reg >> 2);
        bb2[reg] = b2p[ch];
    }

    #pragma unroll
    for (int nf = 0; nf < 2; ++nf)
        #pragma unroll
        for (int reg = 0; reg < 16; ++reg) {
            const float fv = acc2[nf][reg] + bb2[reg];
            acc2[nf][reg] = fv * fv;
        }

    #pragma unroll
    for (int nf = 0; nf < 2; ++nf) {
        float m = acc2[nf][0];
        #pragma unroll
        for (int reg = 1; reg < 16; ++reg) m = fminf(m, acc2[nf][reg]);
        m = fminf(m, __shfl_xor(m, 32));
        if (lane < 32) gm[wv_m][wv_n * 64 + nf * 32 + lane] = m;
    }
    __syncthreads();

    float M2[2];
    #pragma unroll
    for (int nf = 0; nf < 2; ++nf) {
        const int px = wv_n * 64 + nf * 32 + p32;
        M2[nf] = fminf(gm[0][px], gm[1][px]);
    }

    const float* fpx = flowp + (size_t)h * FP_W + (w0 + wv_n * 64 + p32);
    const float* fpy = fpx + (size_t)FP_W * FP_W;
    float dv[2] = {0.f, 0.f}, sx[2] = {0.f, 0.f}, sy[2] = {0.f, 0.f};

    #pragma unroll
    for (int reg = 0; reg < 16; ++reg) {
        const int ch = wv_m * 32 + lh * 4 + (reg & 3) + 8 * (reg >> 2);
        int ki = (ch * 37) >> 8;            // floor(ch/7) for ch<64
        int kj = ch - 7 * ki;
        ki = min(ki, 6);                    // pad channels: d==0, clamp for safety
        kj = min(kj, 6);
        const int off = ki * FP_W + kj;
        #pragma unroll
        for (int nf = 0; nf < 2; ++nf) {
            const float d = __expf(M2[nf] - acc2[nf][reg]);
            dv[nf] += d;
            sx[nf] += d * fpx[off + nf * 32];
            sy[nf] += d * fpy[off + nf * 32];
        }
    }

    #pragma unroll
    for (int nf = 0; nf < 2; ++nf) {
        float d = dv[nf], x = sx[nf], y = sy[nf];
        d += __shfl_xor(d, 32);  x += __shfl_xor(x, 32);  y += __shfl_xor(y, 32);
        if (lane < 32) {
            const int px = wv_n * 64 + nf * 32 + lane;
            dvp[wv_m][px] = d;
            sxp[wv_m][px] = x;
            syp[wv_m][px] = y;
        }
    }
    __syncthreads();

    if (tid < 128) {
        const float D = dvp[0][tid] + dvp[1][tid];
        const float X = sxp[0][tid] + sxp[1][tid];
        const float Y = syp[0][tid] + syp[1][tid];
        const int w = w0 + tid;
        out[(size_t)h * WO + w]                   = X / D;
        out[(size_t)HO * WO + (size_t)h * WO + w] = Y / D;
    }
}

// ---------------------------------------------------------------------------
extern "C" void kernel_launch(void* const* d_in, const int* in_sizes, int n_in,
                              void* d_out, int out_size, void* d_ws, size_t ws_size,
                              hipStream_t stream) {
    const float* reg_feat = (const float*)d_in[0];
    const float* flow     = (const float*)d_in[1];
    const float* wt       = (const float*)d_in[2];
    const float* bt       = (const float*)d_in[3];
    const float* w1       = (const float*)d_in[4];
    const float* b1       = (const float*)d_in[5];
    const float* w2       = (const float*)d_in[6];
    const float* b2       = (const float*)d_in[7];
    float* out = (float*)d_out;
    (void)in_sizes; (void)n_in; (void)out_size;

    float* ws  = (float*)d_ws;
    uint4* wpC = (uint4*)(ws + OFF_WPC);
    float* b2p = ws + OFF_B2P;
    uint4* wpB = (uint4*)(ws + OFF_WPB);
    float* b1p = ws + OFF_B1P;
    uint4* wpA = (uint4*)(ws + OFF_WPA);

    // batch-group width: 4-wide if workspace allows (92.9 MB), else pairwise
    // (46.5 MB, R23-validated). ws_size is constant -> deterministic.
    const size_t need4 = (OFF_BUF + 4 * PB_F32) * sizeof(float);
    const int NB = (ws_size >= need4) ? 4 : 2;

    unsigned short* f0p   = (unsigned short*)(ws + OFF_BUF);
    unsigned short* xp    = f0p + (size_t)NB * F0_US;
    float*          flowp = (float*)(xp + (size_t)NB * XP_US);

    repack<<<26, 256, 0, stream>>>(wt, w1, b1, w2, b2, wpA, wpB, b1p, wpC, b2p);

    const int padBlocks = XP_W + (2 * FP_W * FP_W + 255) / 256;
    for (int pr = 0; pr < 4; pr += NB) {
        const float* xb  = reg_feat + (size_t)pr * CI * HI * WI;
        const float* flb = flow     + (size_t)pr * 2 * HO * WO;
        float*       ob  = out      + (size_t)pr * 2 * HO * WO;
        kPP<<<dim3(padBlocks, NB), 256, 0, stream>>>(xb, flb, xp, flowp);
        kA <<<dim3(1024, NB),      256, 0, stream>>>(xp, wpA, bt, f0p);
        kBC<<<dim3(2048, NB),      256, 0, stream>>>(f0p, wpB, b1p, wpC, b2p, flowp, ob);
    }
}